// Round 1
// baseline (275.299 us; speedup 1.0000x reference)
//
#include <hip/hip_runtime.h>
#include <cstddef>

#define E_DIM 512
#define HID   640
#define NH    10
#define DK    64
#define LTOT  2054
#define NCLS  527
#define NB    4

// ---- workspace layout (floats) ----
#define OFF_PE   0
#define SZ_PE    (LTOT*E_DIM)            // 1,051,648
#define OFF_K    (OFF_PE + SZ_PE)
#define SZ_K     (8*HID)
#define OFF_U    (OFF_K + SZ_K)
#define SZ_U     (8*NH*E_DIM)
#define OFF_C    (OFF_U + SZ_U)
#define SZ_C     (80)
#define OFF_S    (OFF_C + SZ_C)
#define SZ_S     (NB*20*LTOT)
#define OFF_W    (OFF_S + SZ_S)
#define SZ_W     (8*NH*E_DIM)
#define OFF_OR   (OFF_W + SZ_W)
#define SZ_OR    (8*HID)
#define OFF_LN   (OFF_OR + SZ_OR)
#define SZ_LN    (8*HID)

// Select source row pointer for logical feats row n of batch b.
__device__ __forceinline__ const float* row_src(int b, int n,
        const float* au, const float* vi, const float* at,
        const float* vt, const float* bt) {
    if (n < 1024) return au + ((size_t)b*1024 + n)*E_DIM;
    if (n == 1024) return at;
    if (n < 1029) return bt + (size_t)(n-1025)*E_DIM;
    if (n < 2053) return vi + ((size_t)b*1024 + (n-1029))*E_DIM;
    return vt;
}

// K0: positional encoding table pe[n][e], n<2054, e<512
__global__ void ba_pe_kernel(float* __restrict__ pe) {
    int n = blockIdx.x;
    int j = threadIdx.x;                     // 0..255 -> pair index
    const float kC = -0.017988946039016f;    // -ln(10000)/512
    float div = expf((float)(2*j) * kC);
    float arg = (float)n * div;
    pe[(size_t)n*E_DIM + 2*j]     = sinf(arg);
    pe[(size_t)n*E_DIM + 2*j + 1] = cosf(arg);
}

// K1a: k rows for m in {0,1029}.  grid (10 jtiles, 8 bm), block 256
__global__ void ba_k_kernel(const float* __restrict__ audio, const float* __restrict__ video,
                            const float* __restrict__ pe,
                            const float* __restrict__ Wk, const float* __restrict__ bk,
                            float* __restrict__ kws) {
    int bm = blockIdx.y; int b = bm >> 1; int m = bm & 1;
    int mrow = m ? 1029 : 0;
    const float* src = m ? (video + (size_t)b*1024*E_DIM) : (audio + (size_t)b*1024*E_DIM);
    int t = threadIdx.x;
    __shared__ float frow[E_DIM];
    for (int i = t; i < E_DIM; i += 256) frow[i] = src[i] + pe[(size_t)mrow*E_DIM + i];
    __syncthreads();
    int j  = blockIdx.x*64 + (t & 63);
    int es = t >> 6;                 // 0..3
    float part = 0.f;
    #pragma unroll 8
    for (int e = es*128; e < es*128 + 128; ++e)
        part = fmaf(frow[e], Wk[(size_t)e*HID + j], part);
    __shared__ float red[4][64];
    red[es][t & 63] = part;
    __syncthreads();
    if (t < 64) {
        int jj = blockIdx.x*64 + t;
        kws[(size_t)bm*HID + jj] = bk[jj] + red[0][t] + red[1][t] + red[2][t] + red[3][t];
    }
}

// K1b: u[bm][h][e] = (1/8) * sum_d Wq[e, h*64+d] * k[bm, h*64+d]; also c[bm][h]
// grid (NH, 8), block 256
__global__ void ba_u_kernel(const float* __restrict__ Wq, const float* __restrict__ bq,
                            const float* __restrict__ kws,
                            float* __restrict__ uws, float* __restrict__ cws) {
    int h = blockIdx.x, bm = blockIdx.y, t = threadIdx.x;
    __shared__ float kh[DK];
    if (t < DK) kh[t] = kws[(size_t)bm*HID + h*DK + t];
    __syncthreads();
    for (int e = t; e < E_DIM; e += 256) {
        const float4* wq4 = (const float4*)(Wq + (size_t)e*HID + h*DK);
        float s = 0.f;
        #pragma unroll
        for (int dd = 0; dd < DK/4; ++dd) {
            float4 w4 = wq4[dd];
            float4 k4 = *(const float4*)&kh[dd*4];
            s = fmaf(w4.x, k4.x, s); s = fmaf(w4.y, k4.y, s);
            s = fmaf(w4.z, k4.z, s); s = fmaf(w4.w, k4.w, s);
        }
        uws[((size_t)bm*NH + h)*E_DIM + e] = s * 0.125f;
    }
    if (t == 0) {
        float c = 0.f;
        for (int d = 0; d < DK; ++d) c = fmaf(bq[h*DK + d], kh[d], c);
        cws[bm*NH + h] = c * 0.125f;
    }
}

// K2: scores S[b][p][n] = feats[b,n,:]·u'[b,p,:] + c'[b,p]   (p = m*10+h)
// grid (129, NB), block 320  (16 rows x 20 p)
__global__ __launch_bounds__(320) void ba_scores_kernel(
        const float* __restrict__ audio, const float* __restrict__ video,
        const float* __restrict__ atok, const float* __restrict__ vtok,
        const float* __restrict__ btnk, const float* __restrict__ pe,
        const float* __restrict__ uws, const float* __restrict__ cws,
        float* __restrict__ S) {
    int b = blockIdx.y, t = threadIdx.x;
    __shared__ float ul[20*520];
    __shared__ float cl[20];
    for (int idx = t; idx < 20*E_DIM; idx += 320) {
        int p = idx >> 9, e = idx & 511;
        ul[p*520 + e] = uws[((size_t)b*20 + p)*E_DIM + e];
    }
    if (t < 20) cl[t] = cws[b*20 + t];
    __syncthreads();
    int n = blockIdx.x*16 + (t & 15);
    int p = t >> 4;                          // 0..19
    bool valid = (n < LTOT);
    int nn = valid ? n : 0;
    const float* src = row_src(b, nn, audio, video, atok, vtok, btnk);
    const float4* f4  = (const float4*)src;
    const float4* pe4 = (const float4*)(pe + (size_t)nn*E_DIM);
    const float4* u4  = (const float4*)&ul[p*520];
    float acc = 0.f;
    #pragma unroll 4
    for (int i = 0; i < E_DIM/4; ++i) {
        float4 a = f4[i]; float4 pp = pe4[i]; float4 uu = u4[i];
        acc = fmaf(a.x + pp.x, uu.x, acc);
        acc = fmaf(a.y + pp.y, uu.y, acc);
        acc = fmaf(a.z + pp.z, uu.z, acc);
        acc = fmaf(a.w + pp.w, uu.w, acc);
    }
    if (valid) S[((size_t)b*20 + p)*LTOT + n] = acc + cl[p];
}

// K3: softmax over n per row (80 rows).  grid 80, block 256
__global__ void ba_softmax_kernel(float* __restrict__ S) {
    int r = blockIdx.x, t = threadIdx.x;
    float* row = S + (size_t)r*LTOT;
    __shared__ float sred[256];
    float lmax = -1e30f;
    for (int i = t; i < LTOT; i += 256) lmax = fmaxf(lmax, row[i]);
    sred[t] = lmax; __syncthreads();
    for (int s = 128; s > 0; s >>= 1) {
        if (t < s) sred[t] = fmaxf(sred[t], sred[t+s]);
        __syncthreads();
    }
    float m = sred[0]; __syncthreads();
    float lsum = 0.f;
    for (int i = t; i < LTOT; i += 256) {
        float e = expf(row[i] - m);
        row[i] = e;
        lsum += e;
    }
    sred[t] = lsum; __syncthreads();
    for (int s = 128; s > 0; s >>= 1) {
        if (t < s) sred[t] += sred[t+s];
        __syncthreads();
    }
    float inv = 1.0f / sred[0];
    for (int i = t; i < LTOT; i += 256) row[i] *= inv;
}

// K4: w[b][p][e] += sum_{n in chunk} P[b][p][n] * feats[b][n][e]
// grid (16 nchunks, 4 etiles, NB), block 256 (128 e x 2 p-groups)
__global__ void ba_wsum_kernel(
        const float* __restrict__ audio, const float* __restrict__ video,
        const float* __restrict__ atok, const float* __restrict__ vtok,
        const float* __restrict__ btnk, const float* __restrict__ pe,
        const float* __restrict__ S, float* __restrict__ wws) {
    int b = blockIdx.z, et = blockIdx.y, ncnk = blockIdx.x, t = threadIdx.x;
    int n0 = ncnk*129;
    int cnt = min(129, LTOT - n0);
    __shared__ float Pl[20*132];
    for (int idx = t; idx < 20*129; idx += 256) {
        int p = idx / 129, i = idx % 129;
        int n = n0 + i;
        Pl[p*132 + i] = (n < LTOT) ? S[((size_t)b*20 + p)*LTOT + n] : 0.f;
    }
    __syncthreads();
    int e  = et*128 + (t & 127);
    int pg = t >> 7;                 // 0 or 1
    float acc[10];
    #pragma unroll
    for (int j = 0; j < 10; ++j) acc[j] = 0.f;
    for (int i = 0; i < cnt; ++i) {
        int n = n0 + i;
        const float* src = row_src(b, n, audio, video, atok, vtok, btnk);
        float f = src[e] + pe[(size_t)n*E_DIM + e];
        #pragma unroll
        for (int j = 0; j < 10; ++j)
            acc[j] = fmaf(Pl[(pg*10 + j)*132 + i], f, acc[j]);
    }
    #pragma unroll
    for (int j = 0; j < 10; ++j)
        atomicAdd(&wws[((size_t)b*20 + pg*10 + j)*E_DIM + e], acc[j]);
}

// K5a: out_raw[bm][h*64+d] = w[bm][h]·Wv[:,h*64+d] + bv.  grid (NH, 8), block 256
__global__ void ba_outraw_kernel(const float* __restrict__ wws,
                                 const float* __restrict__ Wv, const float* __restrict__ bv,
                                 float* __restrict__ orow) {
    int h = blockIdx.x, bm = blockIdx.y, t = threadIdx.x;
    __shared__ float wh[E_DIM];
    for (int i = t; i < E_DIM; i += 256) wh[i] = wws[((size_t)bm*NH + h)*E_DIM + i];
    __syncthreads();
    int d = t & 63, es = t >> 6;
    float part = 0.f;
    #pragma unroll 8
    for (int e = es*128; e < es*128 + 128; ++e)
        part = fmaf(wh[e], Wv[(size_t)e*HID + h*DK + d], part);
    __shared__ float red[4][64];
    red[es][d] = part;
    __syncthreads();
    if (t < 64)
        orow[(size_t)bm*HID + h*DK + t] = bv[h*DK + t] + red[0][t] + red[1][t] + red[2][t] + red[3][t];
}

// K5b: layernorm of the 8 rows.  grid 8, block 256
__global__ void ba_ln_kernel(const float* __restrict__ orow,
                             const float* __restrict__ g, const float* __restrict__ bb,
                             float* __restrict__ lnout) {
    int bm = blockIdx.x, t = threadIdx.x;
    const float* row = orow + (size_t)bm*HID;
    float ls = 0.f, lq = 0.f;
    for (int i = t; i < HID; i += 256) { float x = row[i]; ls += x; lq = fmaf(x, x, lq); }
    __shared__ float s1[256], s2[256];
    s1[t] = ls; s2[t] = lq; __syncthreads();
    for (int s = 128; s > 0; s >>= 1) {
        if (t < s) { s1[t] += s1[t+s]; s2[t] += s2[t+s]; }
        __syncthreads();
    }
    float mean = s1[0] * (1.0f/HID);
    float var  = s2[0] * (1.0f/HID) - mean*mean;
    float rstd = rsqrtf(var + 1e-5f);
    for (int i = t; i < HID; i += 256)
        lnout[(size_t)bm*HID + i] = (row[i] - mean) * rstd * g[i] + bb[i];
}

// K5c: out[b][c] += 0.5*(lnA·Wap[:,c] + lnV·Wvp[:,c]) over j-slice (+biases on slice 0)
// grid (3 ctiles, NB, 4 jslices), block 256
__global__ void ba_pred_kernel(const float* __restrict__ lnout,
                               const float* __restrict__ Wap, const float* __restrict__ bap,
                               const float* __restrict__ Wvp, const float* __restrict__ bvp,
                               float* __restrict__ out) {
    int c = blockIdx.x*256 + threadIdx.x;
    if (c >= NCLS) return;
    int b = blockIdx.y, js = blockIdx.z;
    int j0 = js*160;
    const float* A = lnout + (size_t)(b*2 + 0)*HID;
    const float* V = lnout + (size_t)(b*2 + 1)*HID;
    float sa = 0.f, sv = 0.f;
    #pragma unroll 8
    for (int j = j0; j < j0 + 160; ++j) {
        sa = fmaf(A[j], Wap[(size_t)j*NCLS + c], sa);
        sv = fmaf(V[j], Wvp[(size_t)j*NCLS + c], sv);
    }
    float r = 0.5f*(sa + sv);
    if (js == 0) r += 0.5f*(bap[c] + bvp[c]);
    atomicAdd(&out[(size_t)b*NCLS + c], r);
}

extern "C" void kernel_launch(void* const* d_in, const int* in_sizes, int n_in,
                              void* d_out, int out_size, void* d_ws, size_t ws_size,
                              hipStream_t stream) {
    const float* audio = (const float*)d_in[0];
    const float* video = (const float*)d_in[1];
    const float* atok  = (const float*)d_in[2];
    const float* vtok  = (const float*)d_in[3];
    const float* btnk  = (const float*)d_in[4];
    const float* Wk    = (const float*)d_in[5];
    const float* bk    = (const float*)d_in[6];
    const float* Wq    = (const float*)d_in[7];
    const float* bq    = (const float*)d_in[8];
    const float* Wv    = (const float*)d_in[9];
    const float* bv    = (const float*)d_in[10];
    const float* ln_g  = (const float*)d_in[11];
    const float* ln_b  = (const float*)d_in[12];
    const float* Wap   = (const float*)d_in[13];
    const float* bap   = (const float*)d_in[14];
    const float* Wvp   = (const float*)d_in[15];
    const float* bvp   = (const float*)d_in[16];
    float* out = (float*)d_out;
    float* ws  = (float*)d_ws;

    float* pe  = ws + OFF_PE;
    float* kws = ws + OFF_K;
    float* uws = ws + OFF_U;
    float* cws = ws + OFF_C;
    float* S   = ws + OFF_S;
    float* wws = ws + OFF_W;
    float* orw = ws + OFF_OR;
    float* lnw = ws + OFF_LN;

    hipMemsetAsync(wws, 0, SZ_W*sizeof(float), stream);
    hipMemsetAsync(out, 0, (size_t)out_size*sizeof(float), stream);

    ba_pe_kernel<<<LTOT, 256, 0, stream>>>(pe);
    ba_k_kernel<<<dim3(10, 8), 256, 0, stream>>>(audio, video, pe, Wk, bk, kws);
    ba_u_kernel<<<dim3(NH, 8), 256, 0, stream>>>(Wq, bq, kws, uws, cws);
    ba_scores_kernel<<<dim3(129, NB), 320, 0, stream>>>(audio, video, atok, vtok, btnk,
                                                        pe, uws, cws, S);
    ba_softmax_kernel<<<80, 256, 0, stream>>>(S);
    ba_wsum_kernel<<<dim3(16, 4, NB), 256, 0, stream>>>(audio, video, atok, vtok, btnk,
                                                        pe, S, wws);
    ba_outraw_kernel<<<dim3(NH, 8), 256, 0, stream>>>(wws, Wv, bv, orw);
    ba_ln_kernel<<<8, 256, 0, stream>>>(orw, ln_g, ln_b, lnw);
    ba_pred_kernel<<<dim3(3, NB, 4), 256, 0, stream>>>(lnw, Wap, bap, Wvp, bvp, out);
}

// Round 2
// 252.175 us; speedup vs baseline: 1.0917x; 1.0917x over previous
//
#include <hip/hip_runtime.h>
#include <cstddef>

#define E_DIM 512
#define HID   640
#define NH    10
#define DK    64
#define LTOT  2054
#define NCLS  527
#define NB    4
#define KC    (-0.0179889460390157f)   // -ln(10000)/512

#define NCH_W 40      // wsum chunks per batch
#define CRW   52      // rows per wsum chunk (40*52 = 2080 >= 2054)
#define NCH_S 121     // scores chunks per batch
#define CRS   17      // rows per scores chunk (121*17 = 2057 >= 2054)

// ---- workspace layout (floats) ----
#define OFF_S   0
#define SZ_S    (NB*20*LTOT)            // 164,320
#define OFF_M   (OFF_S + SZ_S)
#define SZ_M    80
#define OFF_L   (OFF_M + SZ_M)
#define SZ_L    80
#define OFF_U   (OFF_L + SZ_L)
#define SZ_U    (8*NH*E_DIM)            // 40,960
#define OFF_C   (OFF_U + SZ_U)
#define SZ_C    80
#define OFF_WP  (OFF_C + SZ_C)
#define SZ_WP   (NB*NCH_W*20*E_DIM)     // 1,638,400 (6.55 MB)
#define OFF_OR  (OFF_WP + SZ_WP)
#define SZ_OR   (8*HID)
#define OFF_LN  (OFF_OR + SZ_OR)
#define SZ_LN   (8*HID)

// Source row pointer for logical feats row n of batch b.
__device__ __forceinline__ const float* row_src(int b, int n,
        const float* au, const float* vi, const float* at,
        const float* vt, const float* bt) {
    if (n < 1024) return au + ((size_t)b*1024 + n)*E_DIM;
    if (n == 1024) return at;
    if (n < 1029) return bt + (size_t)(n-1025)*E_DIM;
    if (n < 2053) return vi + ((size_t)b*1024 + (n-1029))*E_DIM;
    return vt;
}

// K1: fused k-row + u-vector + c. grid 8 (bm), block 640.
__global__ __launch_bounds__(640) void ba_ku_kernel(
        const float* __restrict__ audio, const float* __restrict__ video,
        const float* __restrict__ Wk, const float* __restrict__ bk,
        const float* __restrict__ Wq, const float* __restrict__ bq,
        float* __restrict__ uws, float* __restrict__ cws) {
    int bm = blockIdx.x; int b = bm >> 1; int m = bm & 1;
    int mrow = m ? 1029 : 0;
    const float* src = m ? (video + (size_t)b*1024*E_DIM)
                         : (audio + (size_t)b*1024*E_DIM);
    int t = threadIdx.x;
    __shared__ float frow[E_DIM];
    __shared__ float kl[HID];
    if (t < E_DIM) {
        float div = expf((float)(t & ~1) * KC);
        float arg = (float)mrow * div;
        float pe  = (t & 1) ? cosf(arg) : sinf(arg);
        frow[t] = src[t] + pe;
    }
    __syncthreads();
    {   // k[t] for t<640
        float acc = 0.f;
        #pragma unroll 8
        for (int e = 0; e < E_DIM; ++e)
            acc = fmaf(frow[e], Wk[(size_t)e*HID + t], acc);
        kl[t] = acc + bk[t];
    }
    __syncthreads();
    // u: 8 outputs per thread, coalesced store
    for (int s = 0; s < 8; ++s) {
        int o = s*640 + t;
        int h = o >> 9, e = o & 511;
        const float4* wq4 = (const float4*)(Wq + (size_t)e*HID + h*DK);
        const float4* k4  = (const float4*)(kl + h*DK);
        float acc = 0.f;
        #pragma unroll
        for (int d = 0; d < 16; ++d) {
            float4 w = wq4[d]; float4 kk = k4[d];
            acc = fmaf(w.x,kk.x, fmaf(w.y,kk.y, fmaf(w.z,kk.z, fmaf(w.w,kk.w, acc))));
        }
        uws[(size_t)bm*NH*E_DIM + o] = acc * 0.125f;
    }
    if (t < NH) {
        float c = 0.f;
        for (int d = 0; d < DK; ++d) c = fmaf(bq[t*DK + d], kl[t*DK + d], c);
        cws[bm*NH + t] = c * 0.125f;
    }
}

// K2: scores. grid (NCH_S, NB), block 256 = 4 waves x (5 p each); lanes split E.
__global__ __launch_bounds__(256) void ba_scores_kernel(
        const float* __restrict__ audio, const float* __restrict__ video,
        const float* __restrict__ atok, const float* __restrict__ vtok,
        const float* __restrict__ btnk,
        const float* __restrict__ uws, const float* __restrict__ cws,
        float* __restrict__ S) {
    int b = blockIdx.y, chunk = blockIdx.x, t = threadIdx.x;
    int w = t >> 6, lane = t & 63;
    int pbase = w*5;
    int eb = lane*8;
    float4 u0[5], u1[5];
    float cadd[5];
    #pragma unroll
    for (int i = 0; i < 5; ++i) {
        const float4* up = (const float4*)(uws + (size_t)(b*20 + pbase + i)*E_DIM + eb);
        u0[i] = up[0]; u1[i] = up[1];
        cadd[i] = cws[b*20 + pbase + i];
    }
    int r0 = chunk*CRS;
    float sn[4], cn[4], sd[4], cd[4];
    #pragma unroll
    for (int q = 0; q < 4; ++q) {
        float d = expf((float)(eb + 2*q) * KC);
        sd[q] = sinf(d); cd[q] = cosf(d);
        float a = (float)r0 * d;
        sn[q] = sinf(a); cn[q] = cosf(a);
    }
    int rend = min(r0 + CRS, LTOT);
    for (int r = r0; r < rend; ++r) {
        const float* src = row_src(b, r, audio, video, atok, vtok, btnk);
        float4 f0 = *(const float4*)(src + eb);
        float4 f1 = *(const float4*)(src + eb + 4);
        float fp[8];
        fp[0]=f0.x+sn[0]; fp[1]=f0.y+cn[0]; fp[2]=f0.z+sn[1]; fp[3]=f0.w+cn[1];
        fp[4]=f1.x+sn[2]; fp[5]=f1.y+cn[2]; fp[6]=f1.z+sn[3]; fp[7]=f1.w+cn[3];
        #pragma unroll
        for (int q = 0; q < 4; ++q) {
            float s2 = fmaf(sn[q], cd[q],  cn[q]*sd[q]);
            float c2 = fmaf(cn[q], cd[q], -sn[q]*sd[q]);
            sn[q] = s2; cn[q] = c2;
        }
        float acc[5];
        #pragma unroll
        for (int i = 0; i < 5; ++i) {
            float a;
            a = fp[0]*u0[i].x;
            a = fmaf(fp[1], u0[i].y, a);
            a = fmaf(fp[2], u0[i].z, a);
            a = fmaf(fp[3], u0[i].w, a);
            a = fmaf(fp[4], u1[i].x, a);
            a = fmaf(fp[5], u1[i].y, a);
            a = fmaf(fp[6], u1[i].z, a);
            a = fmaf(fp[7], u1[i].w, a);
            acc[i] = a;
        }
        #pragma unroll
        for (int off = 1; off < 64; off <<= 1) {
            #pragma unroll
            for (int i = 0; i < 5; ++i) acc[i] += __shfl_xor(acc[i], off, 64);
        }
        #pragma unroll
        for (int i = 0; i < 5; ++i) acc[i] += cadd[i];
        float v = acc[0];
        v = (lane == 1) ? acc[1] : v;
        v = (lane == 2) ? acc[2] : v;
        v = (lane == 3) ? acc[3] : v;
        v = (lane == 4) ? acc[4] : v;
        if (lane < 5)
            S[(size_t)(b*20 + pbase + lane)*LTOT + r] = v;
    }
}

// K3: softmax stats (m, l) per (b,p) row. grid 80, block 256.
__global__ void ba_stats_kernel(const float* __restrict__ S,
                                float* __restrict__ mws, float* __restrict__ lws) {
    int rix = blockIdx.x, t = threadIdx.x;
    const float* row = S + (size_t)rix*LTOT;
    __shared__ float red[256];
    float lm = -1e30f;
    for (int i = t; i < LTOT; i += 256) lm = fmaxf(lm, row[i]);
    red[t] = lm; __syncthreads();
    for (int s = 128; s; s >>= 1) { if (t < s) red[t] = fmaxf(red[t], red[t+s]); __syncthreads(); }
    float m = red[0]; __syncthreads();
    float ls = 0.f;
    for (int i = t; i < LTOT; i += 256) ls += __expf(row[i] - m);
    red[t] = ls; __syncthreads();
    for (int s = 128; s; s >>= 1) { if (t < s) red[t] += red[t+s]; __syncthreads(); }
    if (t == 0) { mws[rix] = m; lws[rix] = red[0]; }
}

// K4: weighted feature sums, per-chunk partials (no atomics).
// grid (NCH_W, NB), block 256 = 4 waves x 5 p; lanes split E.
__global__ __launch_bounds__(256) void ba_wsum_kernel(
        const float* __restrict__ audio, const float* __restrict__ video,
        const float* __restrict__ atok, const float* __restrict__ vtok,
        const float* __restrict__ btnk,
        const float* __restrict__ S, const float* __restrict__ mws,
        float* __restrict__ wpart) {
    int b = blockIdx.y, chunk = blockIdx.x, t = threadIdx.x;
    int w = t >> 6, lane = t & 63;
    int pbase = w*5, eb = lane*8;
    float m[5];
    #pragma unroll
    for (int i = 0; i < 5; ++i) m[i] = mws[b*20 + pbase + i];
    int r0 = chunk*CRW;
    float sn[4], cn[4], sd[4], cd[4];
    #pragma unroll
    for (int q = 0; q < 4; ++q) {
        float d = expf((float)(eb + 2*q) * KC);
        sd[q] = sinf(d); cd[q] = cosf(d);
        float a = (float)r0 * d;
        sn[q] = sinf(a); cn[q] = cosf(a);
    }
    float acc[5][8];
    #pragma unroll
    for (int i = 0; i < 5; ++i)
        #pragma unroll
        for (int j = 0; j < 8; ++j) acc[i][j] = 0.f;
    int rend = min(r0 + CRW, LTOT);
    for (int r = r0; r < rend; ++r) {
        const float* src = row_src(b, r, audio, video, atok, vtok, btnk);
        float4 f0 = *(const float4*)(src + eb);
        float4 f1 = *(const float4*)(src + eb + 4);
        float fp[8];
        fp[0]=f0.x+sn[0]; fp[1]=f0.y+cn[0]; fp[2]=f0.z+sn[1]; fp[3]=f0.w+cn[1];
        fp[4]=f1.x+sn[2]; fp[5]=f1.y+cn[2]; fp[6]=f1.z+sn[3]; fp[7]=f1.w+cn[3];
        #pragma unroll
        for (int q = 0; q < 4; ++q) {
            float s2 = fmaf(sn[q], cd[q],  cn[q]*sd[q]);
            float c2 = fmaf(cn[q], cd[q], -sn[q]*sd[q]);
            sn[q] = s2; cn[q] = c2;
        }
        #pragma unroll
        for (int i = 0; i < 5; ++i) {
            float wgt = __expf(S[(size_t)(b*20 + pbase + i)*LTOT + r] - m[i]);
            #pragma unroll
            for (int j = 0; j < 8; ++j) acc[i][j] = fmaf(wgt, fp[j], acc[i][j]);
        }
    }
    #pragma unroll
    for (int i = 0; i < 5; ++i) {
        float* dst = wpart + ((size_t)(b*NCH_W + chunk)*20 + pbase + i)*E_DIM + eb;
        float4 a0 = make_float4(acc[i][0], acc[i][1], acc[i][2], acc[i][3]);
        float4 a1 = make_float4(acc[i][4], acc[i][5], acc[i][6], acc[i][7]);
        *(float4*)dst       = a0;
        *(float4*)(dst + 4) = a1;
    }
}

// K5: reduce partials, apply 1/l, project through Wv. grid (NH, 8), block 256.
__global__ __launch_bounds__(256) void ba_outraw_kernel(
        const float* __restrict__ wpart, const float* __restrict__ lws,
        const float* __restrict__ Wv, const float* __restrict__ bv,
        float* __restrict__ orow) {
    int h = blockIdx.x, bm = blockIdx.y, t = threadIdx.x;
    int b = bm >> 1, m = bm & 1, p = m*10 + h;
    __shared__ float wh[E_DIM];
    float inv_l = 1.0f / lws[b*20 + p];
    for (int e = t; e < E_DIM; e += 256) {
        float s = 0.f;
        #pragma unroll 8
        for (int ch = 0; ch < NCH_W; ++ch)
            s += wpart[((size_t)(b*NCH_W + ch)*20 + p)*E_DIM + e];
        wh[e] = s * inv_l;
    }
    __syncthreads();
    int d = t & 63, es = t >> 6;
    float part = 0.f;
    #pragma unroll 8
    for (int e = es*128; e < es*128 + 128; ++e)
        part = fmaf(wh[e], Wv[(size_t)e*HID + h*DK + d], part);
    __shared__ float red[4][64];
    red[es][d] = part;
    __syncthreads();
    if (t < 64)
        orow[(size_t)bm*HID + h*DK + t] = bv[h*DK + t]
            + red[0][t] + red[1][t] + red[2][t] + red[3][t];
}

// K6: layernorm of the 8 rows. grid 8, block 256.
__global__ void ba_ln_kernel(const float* __restrict__ orow,
                             const float* __restrict__ g, const float* __restrict__ bb,
                             float* __restrict__ lnout) {
    int bm = blockIdx.x, t = threadIdx.x;
    const float* row = orow + (size_t)bm*HID;
    float ls = 0.f, lq = 0.f;
    for (int i = t; i < HID; i += 256) { float x = row[i]; ls += x; lq = fmaf(x, x, lq); }
    __shared__ float s1[256], s2[256];
    s1[t] = ls; s2[t] = lq; __syncthreads();
    for (int s = 128; s; s >>= 1) {
        if (t < s) { s1[t] += s1[t+s]; s2[t] += s2[t+s]; }
        __syncthreads();
    }
    float mean = s1[0] * (1.0f/HID);
    float var  = s2[0] * (1.0f/HID) - mean*mean;
    float rstd = rsqrtf(var + 1e-5f);
    for (int i = t; i < HID; i += 256)
        lnout[(size_t)bm*HID + i] = (row[i] - mean) * rstd * g[i] + bb[i];
}

// K7: class predictions, j-sliced atomics. grid (3, NB, 8), block 256.
__global__ void ba_pred_kernel(const float* __restrict__ lnout,
                               const float* __restrict__ Wap, const float* __restrict__ bap,
                               const float* __restrict__ Wvp, const float* __restrict__ bvp,
                               float* __restrict__ out) {
    int c = blockIdx.x*256 + threadIdx.x;
    if (c >= NCLS) return;
    int b = blockIdx.y, js = blockIdx.z;
    int j0 = js*80;
    const float* A = lnout + (size_t)(b*2 + 0)*HID;
    const float* V = lnout + (size_t)(b*2 + 1)*HID;
    float sa = 0.f, sv = 0.f;
    #pragma unroll 8
    for (int j = j0; j < j0 + 80; ++j) {
        sa = fmaf(A[j], Wap[(size_t)j*NCLS + c], sa);
        sv = fmaf(V[j], Wvp[(size_t)j*NCLS + c], sv);
    }
    float r = 0.5f*(sa + sv);
    if (js == 0) r += 0.5f*(bap[c] + bvp[c]);
    atomicAdd(&out[(size_t)b*NCLS + c], r);
}

extern "C" void kernel_launch(void* const* d_in, const int* in_sizes, int n_in,
                              void* d_out, int out_size, void* d_ws, size_t ws_size,
                              hipStream_t stream) {
    const float* audio = (const float*)d_in[0];
    const float* video = (const float*)d_in[1];
    const float* atok  = (const float*)d_in[2];
    const float* vtok  = (const float*)d_in[3];
    const float* btnk  = (const float*)d_in[4];
    const float* Wk    = (const float*)d_in[5];
    const float* bk    = (const float*)d_in[6];
    const float* Wq    = (const float*)d_in[7];
    const float* bq    = (const float*)d_in[8];
    const float* Wv    = (const float*)d_in[9];
    const float* bv    = (const float*)d_in[10];
    const float* ln_g  = (const float*)d_in[11];
    const float* ln_b  = (const float*)d_in[12];
    const float* Wap   = (const float*)d_in[13];
    const float* bap   = (const float*)d_in[14];
    const float* Wvp   = (const float*)d_in[15];
    const float* bvp   = (const float*)d_in[16];
    float* out = (float*)d_out;
    float* ws  = (float*)d_ws;

    float* S     = ws + OFF_S;
    float* mws   = ws + OFF_M;
    float* lws   = ws + OFF_L;
    float* uws   = ws + OFF_U;
    float* cws   = ws + OFF_C;
    float* wpart = ws + OFF_WP;
    float* orw   = ws + OFF_OR;
    float* lnw   = ws + OFF_LN;

    hipMemsetAsync(out, 0, (size_t)out_size*sizeof(float), stream);

    ba_ku_kernel<<<8, 640, 0, stream>>>(audio, video, Wk, bk, Wq, bq, uws, cws);
    ba_scores_kernel<<<dim3(NCH_S, NB), 256, 0, stream>>>(audio, video, atok, vtok, btnk,
                                                          uws, cws, S);
    ba_stats_kernel<<<80, 256, 0, stream>>>(S, mws, lws);
    ba_wsum_kernel<<<dim3(NCH_W, NB), 256, 0, stream>>>(audio, video, atok, vtok, btnk,
                                                        S, mws, wpart);
    ba_outraw_kernel<<<dim3(NH, 8), 256, 0, stream>>>(wpart, lws, Wv, bv, orw);
    ba_ln_kernel<<<8, 256, 0, stream>>>(orw, ln_g, ln_b, lnw);
    ba_pred_kernel<<<dim3(3, NB, 8), 256, 0, stream>>>(lnw, Wap, bap, Wvp, bvp, out);
}

// Round 3
// 197.478 us; speedup vs baseline: 1.3941x; 1.2770x over previous
//
#include <hip/hip_runtime.h>
#include <cstddef>

#define E_DIM 512
#define HID   640
#define NH    10
#define DK    64
#define LTOT  2054
#define NCLS  527
#define NB    4
#define KC    (-0.0179889460390157f)   // -ln(10000)/512

#define NCH   40      // chunks per batch for the fused pass
#define CRW   52      // rows per chunk (40*52 = 2080 >= 2054)

// ---- workspace layout (floats), total ~6.8 MB ----
#define OFF_U   0
#define SZ_U    (8*NH*E_DIM)            // 40,960
#define OFF_C   (OFF_U + SZ_U)
#define SZ_C    80
#define OFF_WP  (OFF_C + SZ_C)
#define SZ_WP   (NB*NCH*20*E_DIM)       // 1,638,400
#define OFF_MC  (OFF_WP + SZ_WP)
#define SZ_MC   (NB*NCH*20)             // 3,200
#define OFF_LC  (OFF_MC + SZ_MC)
#define SZ_LC   (NB*NCH*20)
#define OFF_OR  (OFF_LC + SZ_LC)
#define SZ_OR   (8*HID)
#define OFF_LN  (OFF_OR + SZ_OR)
#define SZ_LN   (8*HID)

// Source row pointer for logical feats row n of batch b.
__device__ __forceinline__ const float* row_src(int b, int n,
        const float* au, const float* vi, const float* at,
        const float* vt, const float* bt) {
    if (n < 1024) return au + ((size_t)b*1024 + n)*E_DIM;
    if (n == 1024) return at;
    if (n < 1029) return bt + (size_t)(n-1025)*E_DIM;
    if (n < 2053) return vi + ((size_t)b*1024 + (n-1029))*E_DIM;
    return vt;
}

// K1: per-(h,bm) k-fragment + u-vector + c. grid (NH, 8), block 256.
__global__ __launch_bounds__(256) void ba_ku_kernel(
        const float* __restrict__ audio, const float* __restrict__ video,
        const float* __restrict__ Wk, const float* __restrict__ bk,
        const float* __restrict__ Wq, const float* __restrict__ bq,
        float* __restrict__ uws, float* __restrict__ cws) {
    int h = blockIdx.x, bm = blockIdx.y;
    int b = bm >> 1, m = bm & 1;
    int mrow = m ? 1029 : 0;
    const float* src = m ? (video + (size_t)b*1024*E_DIM)
                         : (audio + (size_t)b*1024*E_DIM);
    int t = threadIdx.x;
    __shared__ float frow[E_DIM];
    __shared__ __align__(16) float kl[DK];
    __shared__ float red[4][DK];
    for (int i = t; i < E_DIM; i += 256) {
        float div = expf((float)(i & ~1) * KC);
        float arg = (float)mrow * div;
        float pe  = (i & 1) ? cosf(arg) : sinf(arg);
        frow[i] = src[i] + pe;
    }
    __syncthreads();
    int d = t & 63, es = t >> 6;
    const float* wkcol = Wk + (size_t)(h*DK) + d;
    float part = 0.f;
    #pragma unroll 8
    for (int e = es*128; e < es*128 + 128; ++e)
        part = fmaf(frow[e], wkcol[(size_t)e*HID], part);
    red[es][d] = part;
    __syncthreads();
    if (t < DK)
        kl[t] = bk[h*DK + t] + red[0][t] + red[1][t] + red[2][t] + red[3][t];
    __syncthreads();
    // u: 2 e's per thread, vectorized over d
    #pragma unroll
    for (int s = 0; s < 2; ++s) {
        int e = s*256 + t;
        const float4* wq4 = (const float4*)(Wq + (size_t)e*HID + h*DK);
        const float4* k4  = (const float4*)kl;
        float acc = 0.f;
        #pragma unroll
        for (int d4 = 0; d4 < 16; ++d4) {
            float4 w = wq4[d4]; float4 kk = k4[d4];
            acc = fmaf(w.x,kk.x, fmaf(w.y,kk.y, fmaf(w.z,kk.z, fmaf(w.w,kk.w, acc))));
        }
        uws[((size_t)bm*NH + h)*E_DIM + e] = acc * 0.125f;
    }
    if (t < DK) {   // c = 0.125 * bq_h . k_h  (wave 0 butterfly)
        float prod = bq[h*DK + t] * kl[t];
        #pragma unroll
        for (int off = 1; off < 64; off <<= 1) prod += __shfl_xor(prod, off, 64);
        if (t == 0) cws[bm*NH + h] = prod * 0.125f;
    }
}

// K2: fused scores + online softmax + weighted feature sum.
// grid (NCH, NB), block 256 = 4 waves x 5 p each; lanes split E (8 each).
__global__ __launch_bounds__(256) void ba_fused_kernel(
        const float* __restrict__ audio, const float* __restrict__ video,
        const float* __restrict__ atok, const float* __restrict__ vtok,
        const float* __restrict__ btnk,
        const float* __restrict__ uws, const float* __restrict__ cws,
        float* __restrict__ wpart, float* __restrict__ mcs,
        float* __restrict__ lcs) {
    int b = blockIdx.y, chunk = blockIdx.x, t = threadIdx.x;
    int w = t >> 6, lane = t & 63;
    int pbase = w*5, eb = lane*8;
    float4 u0[5], u1[5];
    float cadd[5];
    #pragma unroll
    for (int i = 0; i < 5; ++i) {
        const float4* up = (const float4*)(uws + (size_t)(b*20 + pbase + i)*E_DIM + eb);
        u0[i] = up[0]; u1[i] = up[1];
        cadd[i] = cws[b*20 + pbase + i];
    }
    int r0 = chunk*CRW;
    float sn[4], cn[4], sd[4], cd[4];
    #pragma unroll
    for (int q = 0; q < 4; ++q) {
        float dv = expf((float)(eb + 2*q) * KC);
        sd[q] = sinf(dv); cd[q] = cosf(dv);
        float a = (float)r0 * dv;
        sn[q] = sinf(a); cn[q] = cosf(a);
    }
    float m[5], l[5], acc[5][8];
    #pragma unroll
    for (int i = 0; i < 5; ++i) {
        m[i] = -1e30f; l[i] = 0.f;
        #pragma unroll
        for (int j = 0; j < 8; ++j) acc[i][j] = 0.f;
    }
    int rend = min(r0 + CRW, LTOT);
    for (int r = r0; r < rend; ++r) {
        const float* src = row_src(b, r, audio, video, atok, vtok, btnk);
        float4 f0 = *(const float4*)(src + eb);
        float4 f1 = *(const float4*)(src + eb + 4);
        float fp[8];
        fp[0]=f0.x+sn[0]; fp[1]=f0.y+cn[0]; fp[2]=f0.z+sn[1]; fp[3]=f0.w+cn[1];
        fp[4]=f1.x+sn[2]; fp[5]=f1.y+cn[2]; fp[6]=f1.z+sn[3]; fp[7]=f1.w+cn[3];
        #pragma unroll
        for (int q = 0; q < 4; ++q) {
            float s2 = fmaf(sn[q], cd[q],  cn[q]*sd[q]);
            float c2 = fmaf(cn[q], cd[q], -sn[q]*sd[q]);
            sn[q] = s2; cn[q] = c2;
        }
        float s[5];
        #pragma unroll
        for (int i = 0; i < 5; ++i) {
            float a;
            a = fp[0]*u0[i].x;
            a = fmaf(fp[1], u0[i].y, a);
            a = fmaf(fp[2], u0[i].z, a);
            a = fmaf(fp[3], u0[i].w, a);
            a = fmaf(fp[4], u1[i].x, a);
            a = fmaf(fp[5], u1[i].y, a);
            a = fmaf(fp[6], u1[i].z, a);
            a = fmaf(fp[7], u1[i].w, a);
            s[i] = a;
        }
        #pragma unroll
        for (int off = 1; off < 64; off <<= 1) {
            #pragma unroll
            for (int i = 0; i < 5; ++i) s[i] += __shfl_xor(s[i], off, 64);
        }
        #pragma unroll
        for (int i = 0; i < 5; ++i) {
            float sc = s[i] + cadd[i];
            if (sc > m[i]) {            // wave-uniform: all lanes share sc,m
                float scale = __expf(m[i] - sc);
                m[i] = sc;
                l[i] = fmaf(l[i], scale, 1.f);
                #pragma unroll
                for (int j = 0; j < 8; ++j)
                    acc[i][j] = fmaf(acc[i][j], scale, fp[j]);
            } else {
                float wg = __expf(sc - m[i]);
                l[i] += wg;
                #pragma unroll
                for (int j = 0; j < 8; ++j)
                    acc[i][j] = fmaf(wg, fp[j], acc[i][j]);
            }
        }
    }
    #pragma unroll
    for (int i = 0; i < 5; ++i) {
        float* dst = wpart + ((size_t)(b*NCH + chunk)*20 + pbase + i)*E_DIM + eb;
        *(float4*)dst       = make_float4(acc[i][0], acc[i][1], acc[i][2], acc[i][3]);
        *(float4*)(dst + 4) = make_float4(acc[i][4], acc[i][5], acc[i][6], acc[i][7]);
    }
    float mv = m[0], lv = l[0];
    mv = (lane==1)?m[1]:mv; lv = (lane==1)?l[1]:lv;
    mv = (lane==2)?m[2]:mv; lv = (lane==2)?l[2]:lv;
    mv = (lane==3)?m[3]:mv; lv = (lane==3)?l[3]:lv;
    mv = (lane==4)?m[4]:mv; lv = (lane==4)?l[4]:lv;
    if (lane < 5) {
        size_t ix = (size_t)(b*NCH + chunk)*20 + pbase + lane;
        mcs[ix] = mv;
        lcs[ix] = lv;
    }
}

// K3: reduce chunk partials with softmax rescale, project through Wv.
// grid (NH, 8), block 256.
__global__ __launch_bounds__(256) void ba_outraw_kernel(
        const float* __restrict__ wpart, const float* __restrict__ mcs,
        const float* __restrict__ lcs,
        const float* __restrict__ Wv, const float* __restrict__ bv,
        float* __restrict__ orow) {
    int h = blockIdx.x, bm = blockIdx.y, t = threadIdx.x;
    int b = bm >> 1, m = bm & 1, p = m*10 + h;
    __shared__ float coefs[NCH];
    __shared__ float wh[E_DIM];
    float M = -1e30f;
    for (int c = 0; c < NCH; ++c)
        M = fmaxf(M, mcs[(size_t)(b*NCH + c)*20 + p]);
    float L = 0.f;
    for (int c = 0; c < NCH; ++c)
        L += lcs[(size_t)(b*NCH + c)*20 + p] * __expf(mcs[(size_t)(b*NCH + c)*20 + p] - M);
    float invL = 1.0f / L;
    if (t < NCH)
        coefs[t] = __expf(mcs[(size_t)(b*NCH + t)*20 + p] - M) * invL;
    __syncthreads();
    #pragma unroll
    for (int s = 0; s < 2; ++s) {
        int e = s*256 + t;
        float acc = 0.f;
        for (int c = 0; c < NCH; ++c)
            acc = fmaf(wpart[((size_t)(b*NCH + c)*20 + p)*E_DIM + e], coefs[c], acc);
        wh[e] = acc;
    }
    __syncthreads();
    int d = t & 63, es = t >> 6;
    float part = 0.f;
    #pragma unroll 8
    for (int e = es*128; e < es*128 + 128; ++e)
        part = fmaf(wh[e], Wv[(size_t)e*HID + h*DK + d], part);
    __shared__ float red[4][64];
    red[es][d] = part;
    __syncthreads();
    if (t < 64)
        orow[(size_t)bm*HID + h*DK + t] = bv[h*DK + t]
            + red[0][t] + red[1][t] + red[2][t] + red[3][t];
}

// K4: layernorm of the 8 rows. grid 8, block 256.
__global__ void ba_ln_kernel(const float* __restrict__ orow,
                             const float* __restrict__ g, const float* __restrict__ bb,
                             float* __restrict__ lnout) {
    int bm = blockIdx.x, t = threadIdx.x;
    const float* row = orow + (size_t)bm*HID;
    float ls = 0.f, lq = 0.f;
    for (int i = t; i < HID; i += 256) { float x = row[i]; ls += x; lq = fmaf(x, x, lq); }
    __shared__ float s1[256], s2[256];
    s1[t] = ls; s2[t] = lq; __syncthreads();
    for (int s = 128; s; s >>= 1) {
        if (t < s) { s1[t] += s1[t+s]; s2[t] += s2[t+s]; }
        __syncthreads();
    }
    float mean = s1[0] * (1.0f/HID);
    float var  = s2[0] * (1.0f/HID) - mean*mean;
    float rstd = rsqrtf(var + 1e-5f);
    for (int i = t; i < HID; i += 256)
        lnout[(size_t)bm*HID + i] = (row[i] - mean) * rstd * g[i] + bb[i];
}

// K5: class predictions, j-sliced atomics. grid (3, NB, 8), block 256.
__global__ void ba_pred_kernel(const float* __restrict__ lnout,
                               const float* __restrict__ Wap, const float* __restrict__ bap,
                               const float* __restrict__ Wvp, const float* __restrict__ bvp,
                               float* __restrict__ out) {
    int c = blockIdx.x*256 + threadIdx.x;
    if (c >= NCLS) return;
    int b = blockIdx.y, js = blockIdx.z;
    int j0 = js*80;
    const float* A = lnout + (size_t)(b*2 + 0)*HID;
    const float* V = lnout + (size_t)(b*2 + 1)*HID;
    float sa = 0.f, sv = 0.f;
    #pragma unroll 8
    for (int j = j0; j < j0 + 80; ++j) {
        sa = fmaf(A[j], Wap[(size_t)j*NCLS + c], sa);
        sv = fmaf(V[j], Wvp[(size_t)j*NCLS + c], sv);
    }
    float r = 0.5f*(sa + sv);
    if (js == 0) r += 0.5f*(bap[c] + bvp[c]);
    atomicAdd(&out[(size_t)b*NCLS + c], r);
}

extern "C" void kernel_launch(void* const* d_in, const int* in_sizes, int n_in,
                              void* d_out, int out_size, void* d_ws, size_t ws_size,
                              hipStream_t stream) {
    const float* audio = (const float*)d_in[0];
    const float* video = (const float*)d_in[1];
    const float* atok  = (const float*)d_in[2];
    const float* vtok  = (const float*)d_in[3];
    const float* btnk  = (const float*)d_in[4];
    const float* Wk    = (const float*)d_in[5];
    const float* bk    = (const float*)d_in[6];
    const float* Wq    = (const float*)d_in[7];
    const float* bq    = (const float*)d_in[8];
    const float* Wv    = (const float*)d_in[9];
    const float* bv    = (const float*)d_in[10];
    const float* ln_g  = (const float*)d_in[11];
    const float* ln_b  = (const float*)d_in[12];
    const float* Wap   = (const float*)d_in[13];
    const float* bap   = (const float*)d_in[14];
    const float* Wvp   = (const float*)d_in[15];
    const float* bvp   = (const float*)d_in[16];
    float* out = (float*)d_out;
    float* ws  = (float*)d_ws;

    float* uws   = ws + OFF_U;
    float* cws   = ws + OFF_C;
    float* wpart = ws + OFF_WP;
    float* mcs   = ws + OFF_MC;
    float* lcs   = ws + OFF_LC;
    float* orw   = ws + OFF_OR;
    float* lnw   = ws + OFF_LN;

    hipMemsetAsync(out, 0, (size_t)out_size*sizeof(float), stream);

    ba_ku_kernel<<<dim3(NH, 8), 256, 0, stream>>>(audio, video, Wk, bk, Wq, bq, uws, cws);
    ba_fused_kernel<<<dim3(NCH, NB), 256, 0, stream>>>(audio, video, atok, vtok, btnk,
                                                       uws, cws, wpart, mcs, lcs);
    ba_outraw_kernel<<<dim3(NH, 8), 256, 0, stream>>>(wpart, mcs, lcs, Wv, bv, orw);
    ba_ln_kernel<<<8, 256, 0, stream>>>(orw, ln_g, ln_b, lnw);
    ba_pred_kernel<<<dim3(3, NB, 8), 256, 0, stream>>>(lnw, Wap, bap, Wvp, bvp, out);
}